// Round 16
// baseline (3415.747 us; speedup 1.0000x reference)
//
#include <hip/hip_runtime.h>
#include <hip/hip_bf16.h>
#include <math.h>

typedef float in_t;
typedef float out_t;

__device__ __forceinline__ float ldi(const in_t* p, size_t i) { return (float)p[i]; }

#define DMODEL 192
#define NTOK   197
#define BT_    80
#define ROWS_  (BT_*NTOK)   // 15760

__device__ __forceinline__ float gelu_f(float v) {
  return 0.5f*v*(1.f + tanhf(0.7978845608028654f*(v + 0.044715f*v*v*v)));
}

__device__ __forceinline__ short f2bf(float f) {
  union { float f; unsigned u; } v; v.f = f;
  unsigned r = v.u + 0x7FFFu + ((v.u >> 16) & 1u);
  return (short)(r >> 16);
}

typedef __attribute__((ext_vector_type(8))) short bfrag;
typedef __attribute__((ext_vector_type(4))) float f32x4;

// ============ weight convert+transpose: W[l][K][N] fp32 -> O[l][N][K] bf16 ====
__global__ __launch_bounds__(256)
void wconv_k(const float* __restrict__ W, short* __restrict__ O, int K, int N)
{
  __shared__ float tile[32][33];
  const int l = blockIdx.z;
  const int k0 = blockIdx.y*32, n0 = blockIdx.x*32;
  const float* Wl = W + (size_t)l*K*N;
  short* Ol = O + (size_t)l*K*N;
  const int tx = threadIdx.x & 31, ty = threadIdx.x >> 5;
  #pragma unroll
  for (int r = ty; r < 32; r += 8) {
    int k = k0 + r, n = n0 + tx;
    tile[r][tx] = (k < K && n < N) ? Wl[(size_t)k*N + n] : 0.f;
  }
  __syncthreads();
  #pragma unroll
  for (int r = ty; r < 32; r += 8) {
    int n = n0 + r, k = k0 + tx;
    if (n < N && k < K) Ol[(size_t)n*K + k] = f2bf(tile[tx][r]);
  }
}

// ============ gemmW: full-K-chunk (192) staged MFMA GEMM ====================
template<int EPI, int ABF, int OBF>
__global__ __launch_bounds__(256)
void gemmW_k(const void* __restrict__ Ain, const short* __restrict__ Wt,
             const float* __restrict__ bias, const float* __restrict__ R,
             void* __restrict__ Cout, float* __restrict__ Cout2,
             int M, int N, int K)
{
  constexpr int LP = 200;
  __shared__ short Asb[64][LP];
  __shared__ short Bsb[64][LP];
  const int t = threadIdx.x;
  const int w = t >> 6, lane = t & 63;
  const int bm0 = blockIdx.y*64, bn0 = blockIdx.x*64;
  const int sr = t >> 2;
  const int sk = (t & 3) * 8;
  f32x4 acc[4] = {};

  for (int k0 = 0; k0 < K; k0 += 192) {
    const int gm = bm0 + sr;
    #pragma unroll
    for (int cc = 0; cc < 6; ++cc) {
      const int kk = cc*32 + sk;
      short y[8] = {0,0,0,0,0,0,0,0};
      if (gm < M) {
        if (ABF == 0) {
          const float* ap = (const float*)Ain + (size_t)gm*K + k0 + kk;
          float4 v0 = *(const float4*)ap;
          float4 v1 = *(const float4*)(ap + 4);
          y[0]=f2bf(v0.x); y[1]=f2bf(v0.y); y[2]=f2bf(v0.z); y[3]=f2bf(v0.w);
          y[4]=f2bf(v1.x); y[5]=f2bf(v1.y); y[6]=f2bf(v1.z); y[7]=f2bf(v1.w);
        } else {
          *(bfrag*)y = *(const bfrag*)((const short*)Ain + (size_t)gm*K + k0 + kk);
        }
      }
      *(bfrag*)&Asb[sr][kk] = *(bfrag*)y;
      bfrag bv = *(const bfrag*)(Wt + (size_t)(bn0 + sr)*K + k0 + kk);
      *(bfrag*)&Bsb[sr][kk] = bv;
    }
    __syncthreads();
    const int fr = lane & 15, g8 = (lane >> 4) * 8;
    #pragma unroll
    for (int ks = 0; ks < 6; ++ks) {
      bfrag af = *(const bfrag*)&Asb[w*16 + fr][ks*32 + g8];
      #pragma unroll
      for (int nt = 0; nt < 4; ++nt) {
        bfrag bf = *(const bfrag*)&Bsb[nt*16 + fr][ks*32 + g8];
        acc[nt] = __builtin_amdgcn_mfma_f32_16x16x32_bf16(af, bf, acc[nt], 0, 0, 0);
      }
    }
    __syncthreads();
  }
  const int col = lane & 15, rg = (lane >> 4) * 4;
  #pragma unroll
  for (int nt = 0; nt < 4; ++nt) {
    int gn = bn0 + nt*16 + col;
    float bv = bias ? bias[gn] : 0.f;
    #pragma unroll
    for (int r = 0; r < 4; ++r) {
      int gm = bm0 + w*16 + rg + r;
      if (gm < M) {
        float v = acc[nt][r] + bv;
        if (EPI==1) v = gelu_f(v);
        if (EPI==2) v += R[(size_t)gm*N + gn];
        if (OBF==0)      ((float*)Cout)[(size_t)gm*N + gn] = v;
        else if (OBF==1) ((short*)Cout)[(size_t)gm*N + gn] = f2bf(v);
        else {
          if (gn < 384) ((short*)Cout)[(size_t)gm*384 + gn] = f2bf(v);
          else          Cout2[(size_t)gm*192 + (gn - 384)] = v;
        }
      }
    }
  }
}

// ============ ffn_k v2: barrier-free fused fc1+fc2, bit-identical ===========
// A staged once (one barrier). W1/W2 fragments read directly from global
// (each once per block; L2-hot across 247 blocks). FF kept in two 384-col
// half-tiles in LDS; rows are wave-private bands -> no barriers after the
// A-stage. Per-output-tile accumulation chains keep k-ascending order
// (fc1: ks 0..5; fc2: kc 0,1 in half 0 then 2,3 in half 1) -> bit-identical
// to the split gemmW pair / round-15 ffn.
__global__ __launch_bounds__(256)
void ffn_k(const float* __restrict__ Ain, const short* __restrict__ W1t,
           const float* __restrict__ b1, const short* __restrict__ W2t,
           const float* __restrict__ b2, const float* __restrict__ R,
           float* __restrict__ Cout, int M)
{
  __shared__ short As[64][200];
  __shared__ short FF[64][392];     // one 384-col half of fc1 output (+pad)
  const int t = threadIdx.x;
  const int w = t >> 6, lane = t & 63;
  const int bm0 = blockIdx.x*64;
  const int sr = t >> 2;
  const int sk = (t & 3) * 8;
  const int fr = lane & 15, g8 = (lane >> 4) * 8;
  const int col = lane & 15, rg = (lane >> 4) * 4;
  const int row = w*16 + fr;

  // ---- stage A (64 x 192, fp32 -> bf16); the only barrier ----
  {
    const int gm = bm0 + sr;
    #pragma unroll
    for (int cc = 0; cc < 6; ++cc) {
      const int kk = cc*32 + sk;
      short y[8] = {0,0,0,0,0,0,0,0};
      if (gm < M) {
        const float* ap = Ain + (size_t)gm*192 + kk;
        float4 v0 = *(const float4*)ap;
        float4 v1 = *(const float4*)(ap + 4);
        y[0]=f2bf(v0.x); y[1]=f2bf(v0.y); y[2]=f2bf(v0.z); y[3]=f2bf(v0.w);
        y[4]=f2bf(v1.x); y[5]=f2bf(v1.y); y[6]=f2bf(v1.z); y[7]=f2bf(v1.w);
      }
      *(bfrag*)&As[sr][kk] = *(bfrag*)y;
    }
  }
  __syncthreads();

  f32x4 acc2[12] = {};              // fc2: 12 col-tiles x (4 rows/lane)

  #pragma unroll
  for (int half = 0; half < 2; ++half) {
    // ---- fc1 for this half's 6 n-chunks; W1 fragments from global ----
    for (int nc6 = 0; nc6 < 6; ++nc6) {
      const int nc = half*6 + nc6;
      f32x4 a1[4] = {};
      #pragma unroll
      for (int ks = 0; ks < 6; ++ks) {
        bfrag af = *(const bfrag*)&As[row][ks*32 + g8];
        #pragma unroll
        for (int nt = 0; nt < 4; ++nt) {
          bfrag bf = *(const bfrag*)(W1t + (size_t)(nc*64 + nt*16 + fr)*192 + ks*32 + g8);
          a1[nt] = __builtin_amdgcn_mfma_f32_16x16x32_bf16(af, bf, a1[nt], 0, 0, 0);
        }
      }
      #pragma unroll
      for (int nt = 0; nt < 4; ++nt) {
        int gn = nc*64 + nt*16 + col;
        float bv = b1[gn];
        #pragma unroll
        for (int r = 0; r < 4; ++r)
          FF[w*16 + rg + r][nc6*64 + nt*16 + col] = f2bf(gelu_f(a1[nt][r] + bv));
      }
    }
    // ---- fc2 partial over this half's 384 k-values (kc = half*2 + kcl) ----
    #pragma unroll
    for (int kcl = 0; kcl < 2; ++kcl) {
      #pragma unroll
      for (int ks = 0; ks < 6; ++ks) {
        bfrag af = *(const bfrag*)&FF[row][kcl*192 + ks*32 + g8];
        #pragma unroll
        for (int nt = 0; nt < 12; ++nt) {
          bfrag bf = *(const bfrag*)(W2t + (size_t)(nt*16 + fr)*768 + (half*2 + kcl)*192 + ks*32 + g8);
          acc2[nt] = __builtin_amdgcn_mfma_f32_16x16x32_bf16(af, bf, acc2[nt], 0, 0, 0);
        }
      }
    }
  }
  // ---- epilogue: bias + residual (same as split fc2) ----
  #pragma unroll
  for (int nt = 0; nt < 12; ++nt) {
    int gn = nt*16 + col;
    float bv = b2[gn];
    #pragma unroll
    for (int r = 0; r < 4; ++r) {
      int gm = bm0 + w*16 + rg + r;
      if (gm < M) {
        float v = acc2[nt][r] + bv + R[(size_t)gm*192 + gn];
        Cout[(size_t)gm*192 + gn] = v;
      }
    }
  }
}

// ================= LayerNorm over width 192 =================
__global__ __launch_bounds__(256)
void ln_k(const float* __restrict__ x, const in_t* __restrict__ g, const in_t* __restrict__ b,
          float* __restrict__ o, int rows)
{
  int t = threadIdx.x, wave = t>>6, lane = t&63;
  int r = blockIdx.x*4 + wave;
  if (r >= rows) return;
  const float* xr = x + (size_t)r*DMODEL;
  float e0 = xr[lane], e1 = xr[lane+64], e2 = xr[lane+128];
  float s = e0+e1+e2;
  #pragma unroll
  for (int off=32; off; off>>=1) s += __shfl_xor(s, off);
  float mean = s / 192.f;
  float d0=e0-mean, d1=e1-mean, d2=e2-mean;
  float v = d0*d0+d1*d1+d2*d2;
  #pragma unroll
  for (int off=32; off; off>>=1) v += __shfl_xor(v, off);
  float rs = 1.f / sqrtf(v/192.f + 1e-6f);
  float* orow = o + (size_t)r*DMODEL;
  orow[lane]     = d0*rs*ldi(g,lane)     + ldi(b,lane);
  orow[lane+64]  = d1*rs*ldi(g,lane+64)  + ldi(b,lane+64);
  orow[lane+128] = d2*rs*ldi(g,lane+128) + ldi(b,lane+128);
}

// ============ fused gather + LayerNorm ====================================
__global__ __launch_bounds__(256)
void gatherln_k(const float* __restrict__ X, const float* __restrict__ P,
                const int* __restrict__ idx, const in_t* __restrict__ g,
                const in_t* __restrict__ b, float* __restrict__ Xo,
                float* __restrict__ H2, int rows)
{
  int t = threadIdx.x, wave = t>>6, lane = t&63;
  int r = blockIdx.x*4 + wave;
  if (r >= rows) return;
  int bt = r / NTOK, n = r - bt*NTOK;
  int src = idx[(size_t)bt*NTOK + n];
  size_t sb = ((size_t)bt*NTOK + src)*DMODEL;
  float e0 = X[sb+lane]     + P[sb+lane];
  float e1 = X[sb+lane+64]  + P[sb+lane+64];
  float e2 = X[sb+lane+128] + P[sb+lane+128];
  float* xr = Xo + (size_t)r*DMODEL;
  xr[lane] = e0; xr[lane+64] = e1; xr[lane+128] = e2;
  float s = e0+e1+e2;
  #pragma unroll
  for (int off=32; off; off>>=1) s += __shfl_xor(s, off);
  float mean = s / 192.f;
  float d0=e0-mean, d1=e1-mean, d2=e2-mean;
  float v = d0*d0+d1*d1+d2*d2;
  #pragma unroll
  for (int off=32; off; off>>=1) v += __shfl_xor(v, off);
  float rs = 1.f / sqrtf(v/192.f + 1e-6f);
  float* orow = H2 + (size_t)r*DMODEL;
  orow[lane]     = d0*rs*ldi(g,lane)     + ldi(b,lane);
  orow[lane+64]  = d1*rs*ldi(g,lane+64)  + ldi(b,lane+64);
  orow[lane+128] = d2*rs*ldi(g,lane+128) + ldi(b,lane+128);
}

// ================= MFMA fused attention, bf16 operands ====================
template<int DH, int W, int MODE>
__global__ __launch_bounds__(W*64)
void attnB_k(const short* __restrict__ qk, const float* __restrict__ vf,
             short* __restrict__ out, float* __restrict__ attn0,
             int heads, float scale)
{
  constexpr int NSEQ = 197;
  constexpr int NP   = 224;
  constexpr int KG   = DH/8;
  constexpr int CT   = DH/16;
  constexpr int NF   = DH/32;
  __shared__ short Kb[KG][NP][8];
  __shared__ short Vt[NP/8][DH][8];
  __shared__ short Ps[W][NP/8][16][8];

  const int bh = blockIdx.x;
  const int b = bh / heads, h = bh - b*heads;
  const int qks = ((MODE==1) ? 3 : 2)*heads*DH;
  const short* __restrict__ baseqk = qk + (size_t)b*NSEQ*qks;
  const int qo = h*DH, ko = heads*DH + h*DH;
  const int vs = heads*DH;
  const float* __restrict__ basev = (MODE==2) ? (vf + (size_t)b*NSEQ*vs) : nullptr;
  const int vo = (MODE==1) ? (2*heads*DH + h*DH) : (h*DH);
  const int t = threadIdx.x, w = t>>6, lane = t&63;

  {
    short z8[8] = {0,0,0,0,0,0,0,0};
    for (int idx = t; idx < NP*KG; idx += W*64) {
      int j = idx / KG, dg = idx - j*KG;
      bfrag kv = *(bfrag*)z8;
      if (j < NSEQ) kv = *(const bfrag*)(baseqk + (size_t)j*qks + ko + dg*8);
      *(bfrag*)&Kb[dg][j][0] = kv;
    }
  }
  for (int idx = t; idx < NP*DH; idx += W*64) {
    int j = idx / DH, d = idx - j*DH;
    short vv = 0;
    if (j < NSEQ) {
      if (MODE==1) vv = baseqk[(size_t)j*qks + vo + d];
      else         vv = f2bf(basev[(size_t)j*vs + vo + d]);
    }
    Vt[j>>3][d][j&7] = vv;
  }
  __syncthreads();

  const int c = lane & 15, g = lane >> 4, rg = g*4;
  const float NEG = -3.0e38f;

  for (int st = w; st < 13; st += W) {
    const int q0 = st*16;
    int qrow = q0 + c; if (qrow > NSEQ-1) qrow = NSEQ-1;
    bfrag aq[NF];
    {
      const short* qp = baseqk + (size_t)qrow*qks + qo + g*8;
      #pragma unroll
      for (int f = 0; f < NF; ++f) aq[f] = *(const bfrag*)(qp + f*32);
    }
    f32x4 sacc[14];
    #pragma unroll
    for (int jt = 0; jt < 14; ++jt) sacc[jt] = (f32x4){0.f,0.f,0.f,0.f};
    #pragma unroll
    for (int jt = 0; jt < 13; ++jt) {
      #pragma unroll
      for (int f = 0; f < NF; ++f) {
        bfrag bk = *(const bfrag*)&Kb[f*4 + g][jt*16 + c][0];
        sacc[jt] = __builtin_amdgcn_mfma_f32_16x16x32_bf16(aq[f], bk, sacc[jt], 0, 0, 0);
      }
    }
    float m0[4] = {NEG,NEG,NEG,NEG};
    #pragma unroll
    for (int jt = 0; jt < 14; ++jt) {
      const bool valid = (jt < 13) && (jt*16 + c < NSEQ);
      #pragma unroll
      for (int r = 0; r < 4; ++r) {
        float sv = valid ? sacc[jt][r]*scale : NEG;
        sacc[jt][r] = sv;
        m0[r] = fmaxf(m0[r], sv);
      }
    }
    #pragma unroll
    for (int off = 1; off < 16; off <<= 1)
      #pragma unroll
      for (int r = 0; r < 4; ++r) m0[r] = fmaxf(m0[r], __shfl_xor(m0[r], off));
    float sum[4] = {0.f,0.f,0.f,0.f};
    #pragma unroll
    for (int jt = 0; jt < 14; ++jt)
      #pragma unroll
      for (int r = 0; r < 4; ++r) {
        float e = expf(sacc[jt][r] - m0[r]);
        sacc[jt][r] = e;
        sum[r] += e;
      }
    #pragma unroll
    for (int off = 1; off < 16; off <<= 1)
      #pragma unroll
      for (int r = 0; r < 4; ++r) sum[r] += __shfl_xor(sum[r], off);
    float inv[4];
    #pragma unroll
    for (int r = 0; r < 4; ++r) inv[r] = 1.f / sum[r];

    if (attn0 != nullptr && st == 0 && g == 0) {
      #pragma unroll
      for (int jt = 0; jt < 13; ++jt) {
        int j = jt*16 + c;
        if (j < NSEQ) attn0[(size_t)bh*NSEQ + j] = sacc[jt][0]*inv[0];
      }
    }
    #pragma unroll
    for (int jt = 0; jt < 14; ++jt)
      #pragma unroll
      for (int r = 0; r < 4; ++r)
        Ps[w][jt*2 + (c>>3)][rg + r][c&7] = f2bf(sacc[jt][r]);
    f32x4 oacc[CT];
    #pragma unroll
    for (int ct = 0; ct < CT; ++ct) oacc[ct] = (f32x4){0.f,0.f,0.f,0.f};
    #pragma unroll
    for (int kc = 0; kc < 7; ++kc) {
      bfrag ap = *(const bfrag*)&Ps[w][kc*4 + g][c][0];
      #pragma unroll
      for (int ct = 0; ct < CT; ++ct) {
        bfrag bv = *(const bfrag*)&Vt[kc*4 + g][ct*16 + c][0];
        oacc[ct] = __builtin_amdgcn_mfma_f32_16x16x32_bf16(ap, bv, oacc[ct], 0, 0, 0);
      }
    }
    #pragma unroll
    for (int ct = 0; ct < CT; ++ct)
      #pragma unroll
      for (int r = 0; r < 4; ++r) {
        int q = q0 + rg + r;
        if (q < NSEQ)
          out[((size_t)b*NSEQ + q)*(size_t)(heads*DH) + h*DH + ct*16 + c] = f2bf(oacc[ct][r]*inv[r]);
      }
  }
}

// ================= Fused attention v2r (temporal Nseq=6, fp32) ============
template<int DH, int W>
__global__ __launch_bounds__(W*64)
void attn2r_k(const float* __restrict__ qkv, float* __restrict__ out,
              float* __restrict__ attn0, int Nseq, int heads, float scale)
{
  constexpr int QT = 8;
  constexpr int KTS = 204;
  constexpr int NPART = (DH == 64) ? 1 : 2;
  constexpr int DQ   = DH/4;
  constexpr int QPG  = 2;
  __shared__ float Kt[DH * KTS];
  __shared__ float Qt[W][DH][12];
  __shared__ float Ps[W][QT][200];

  const int bh = blockIdx.x;
  const int b = bh / heads, h = bh % heads;
  const int stride = 3 * heads * DH;
  const float* __restrict__ base = qkv + (size_t)b * Nseq * stride;
  const int qo = h * DH, ko = heads * DH + h * DH, vo = 2 * heads * DH + h * DH;
  const int t = threadIdx.x, w = t >> 6, lane = t & 63;

  for (int idx = t; idx < Nseq * DH; idx += W * 64) {
    int j = idx / DH, d0 = idx - j * DH;
    Kt[d0 * KTS + j] = base[(size_t)j * stride + ko + d0];
  }
  __syncthreads();

  const int d = lane & (DH - 1);
  const int nchunks = (Nseq + QT - 1) / QT;
  const int jcmax = (Nseq + 3) >> 2;
  const float NEG = -3.0e38f;
  const float4* Kt4 = (const float4*)Kt;

  const int part = (NPART == 2) ? (lane >> 5) : 0;
  const int qg   = (DH == 64) ? (lane >> 4) : ((lane >> 3) & 3);
  const int dq   = lane & (DQ - 1);
  const int dv   = 4 * dq;

  for (int ic = w; ic < nchunks; ic += W) {
    const int i0 = ic * QT;
    if ((DH == 64) || (lane >> 5) == 0) {
      #pragma unroll
      for (int q = 0; q < QT; ++q) {
        int i = i0 + q;
        Qt[w][d][q] = (i < Nseq) ? base[(size_t)i * stride + qo + d] : 0.f;
      }
    }
    float s[QT][4];
    #pragma unroll
    for (int q = 0; q < QT; ++q)
      #pragma unroll
      for (int u = 0; u < 4; ++u) s[q][u] = 0.f;
    #pragma unroll 4
    for (int dd = 0; dd < DH; ++dd) {
      float4 kv = (lane < 51) ? Kt4[dd * (KTS/4) + lane] : make_float4(0.f,0.f,0.f,0.f);
      float4 qA = *(const float4*)&Qt[w][dd][0];
      float4 qB = *(const float4*)&Qt[w][dd][4];
      float qv[8] = {qA.x, qA.y, qA.z, qA.w, qB.x, qB.y, qB.z, qB.w};
      float kr[4] = {kv.x, kv.y, kv.z, kv.w};
      #pragma unroll
      for (int q = 0; q < QT; ++q)
        #pragma unroll
        for (int u = 0; u < 4; ++u)
          s[q][u] = fmaf(qv[q], kr[u], s[q][u]);
    }
    float inv[QT];
    #pragma unroll
    for (int q = 0; q < QT; ++q) {
      float mx = NEG;
      #pragma unroll
      for (int u = 0; u < 4; ++u) {
        int j = 4*lane + u;
        s[q][u] = (j < Nseq) ? s[q][u]*scale : NEG;
        mx = fmaxf(mx, s[q][u]);
      }
      #pragma unroll
      for (int off = 32; off; off >>= 1) mx = fmaxf(mx, __shfl_xor(mx, off));
      float sum = 0.f;
      #pragma unroll
      for (int u = 0; u < 4; ++u) {
        float p = (4*lane + u < Nseq) ? expf(s[q][u] - mx) : 0.f;
        s[q][u] = p; sum += p;
      }
      #pragma unroll
      for (int off = 32; off; off >>= 1) sum += __shfl_xor(sum, off);
      inv[q] = 1.f / sum;
      if (lane < 50)
        *(float4*)&Ps[w][q][4*lane] = make_float4(s[q][0], s[q][1], s[q][2], s[q][3]);
    }
    if (attn0 != nullptr && i0 == 0) {
      #pragma unroll
      for (int u = 0; u < 4; ++u) {
        int j = 4*lane + u;
        if (j < Nseq) attn0[(size_t)bh*Nseq + j] = s[0][u]*inv[0];
      }
    }
    float o[QPG][4];
    #pragma unroll
    for (int qi = 0; qi < QPG; ++qi) { o[qi][0]=0.f; o[qi][1]=0.f; o[qi][2]=0.f; o[qi][3]=0.f; }
    const float* __restrict__ Vg = base + vo;
    for (int jc = part; jc < jcmax; jc += NPART) {
      const int jb = 4*jc;
      float4 V0 = make_float4(0.f,0.f,0.f,0.f), V1=V0, V2=V0, V3=V0;
      if (jb+0 < Nseq) V0 = *(const float4*)&Vg[(size_t)(jb+0)*stride + dv];
      if (jb+1 < Nseq) V1 = *(const float4*)&Vg[(size_t)(jb+1)*stride + dv];
      if (jb+2 < Nseq) V2 = *(const float4*)&Vg[(size_t)(jb+2)*stride + dv];
      if (jb+3 < Nseq) V3 = *(const float4*)&Vg[(size_t)(jb+3)*stride + dv];
      #pragma unroll
      for (int qi = 0; qi < QPG; ++qi) {
        float4 p4 = *(const float4*)&Ps[w][qg*QPG+qi][jb];
        o[qi][0] = fmaf(p4.w,V3.x, fmaf(p4.z,V2.x, fmaf(p4.y,V1.x, fmaf(p4.x,V0.x, o[qi][0]))));
        o[qi][1] = fmaf(p4.w,V3.y, fmaf(p4.z,V2.y, fmaf(p4.y,V1.y, fmaf(p4.x,V0.y, o[qi][1]))));
        o[qi][2] = fmaf(p4.w,V3.z, fmaf(p4.z,V2.z, fmaf(p4.y,V1.z, fmaf(p4.x,V0.z, o[qi][2]))));
        o[qi][3] = fmaf(p4.w,V3.w, fmaf(p4.z,V2.w, fmaf(p4.y,V1.w, fmaf(p4.x,V0.w, o[qi][3]))));
      }
    }
    if (NPART == 2) {
      #pragma unroll
      for (int qi = 0; qi < QPG; ++qi) {
        o[qi][0] += __shfl_xor(o[qi][0], 32);
        o[qi][1] += __shfl_xor(o[qi][1], 32);
        o[qi][2] += __shfl_xor(o[qi][2], 32);
        o[qi][3] += __shfl_xor(o[qi][3], 32);
      }
    }
    if (part == 0) {
      #pragma unroll
      for (int qi = 0; qi < QPG; ++qi) {
        float iv = inv[qi];
        if (qg == 1) iv = inv[QPG + qi];
        if (qg == 2) iv = inv[2*QPG + qi];
        if (qg == 3) iv = inv[3*QPG + qi];
        int i = i0 + qg*QPG + qi;
        if (i < Nseq) {
          float4 r = make_float4(o[qi][0]*iv, o[qi][1]*iv, o[qi][2]*iv, o[qi][3]*iv);
          *(float4*)&out[((size_t)b*Nseq + i)*(size_t)(heads*DH) + h*DH + dv] = r;
        }
      }
    }
  }
}

// ================= patch extraction (bf16 out) =================
__global__ void patchify_k(const in_t* __restrict__ x, short* __restrict__ A)
{
  int idx = blockIdx.x*256 + threadIdx.x;
  const int total = BT_*196*768;
  if (idx >= total) return;
  int kc = idx % 768;
  int m  = idx / 768;
  int p  = m % 196;
  int bt = m / 196;
  int c  = kc >> 8;
  int py = (kc >> 4) & 15;
  int px = kc & 15;
  int ph = p / 14, pw = p % 14;
  size_t src = (((size_t)bt*3 + c)*224 + (ph*16+py))*224 + (pw*16+px);
  A[idx] = f2bf(ldi(x, src));
}

// ================= assemble tokens =================
__global__ void assemble_k(const float* __restrict__ pt, const in_t* __restrict__ st,
                           const in_t* __restrict__ pe, float* __restrict__ X)
{
  int i = blockIdx.x*256 + threadIdx.x;
  const int total = BT_*NTOK*DMODEL;
  if (i >= total) return;
  int d  = i % DMODEL;
  int n  = (i / DMODEL) % NTOK;
  int bt = i / (DMODEL*NTOK);
  int tt = bt % 5;
  float base = (n == 0) ? ldi(st, d)
                        : pt[((size_t)bt*196 + (n-1))*DMODEL + d];
  X[i] = base + ldi(pe, ((size_t)tt*NTOK + n)*DMODEL + d);
}

// ============ fused ATS score + sampling ==================================
__global__ __launch_bounds__(256)
void scoresample_k(const float* __restrict__ attn0, const float* __restrict__ Vf,
                   int* __restrict__ idxout)
{
  __shared__ float S[196];
  __shared__ float cdf[196];
  int b = blockIdx.x, t = threadIdx.x;
  if (t < 196) {
    int j = t + 1;
    float acc = 0.f;
    #pragma unroll
    for (int h = 0; h < 6; ++h) {
      float a0 = attn0[((size_t)b*6 + h)*NTOK + j];
      const float* v = Vf + ((size_t)b*NTOK + j)*192 + h*32;
      float ss = 0.f;
      #pragma unroll
      for (int d = 0; d < 32; ++d) ss += v[d]*v[d];
      acc += a0 * sqrtf(ss);
    }
    S[t] = acc / 6.0f;
  }
  __syncthreads();
  if (t == 0) {
    float tot = 0.f;
    for (int k = 0; k < 196; ++k) tot += S[k];
    float denom = tot + 1e-8f;
    float run = 0.f;
    for (int k = 0; k < 196; ++k) { run += S[k] / denom; cdf[k] = run; }
    idxout[(size_t)b*NTOK] = 0;
  }
  __syncthreads();
  if (t < 196) {
    float u = ((float)t + 0.5f) / 196.0f;
    int cnt = 0;
    for (int k = 0; k < 196; ++k) cnt += (cdf[k] < u) ? 1 : 0;
    int c = cnt > 195 ? 195 : cnt;
    idxout[(size_t)b*NTOK + 1 + t] = c + 1;
  }
}

// ================= build temporal sequence =================
__global__ void build_xc_k(const float* __restrict__ X, const in_t* __restrict__ tt,
                           float* __restrict__ xc)
{
  int i = blockIdx.x*256 + threadIdx.x;
  const int total = 16*6*DMODEL;
  if (i >= total) return;
  int d = i % DMODEL;
  int n = (i / DMODEL) % 6;
  int b = i / (DMODEL*6);
  xc[i] = (n == 0) ? ldi(tt, d)
                   : X[(((size_t)b*5 + (n-1))*NTOK + 0)*DMODEL + d];
}

// ================= maxpool + final LN + MLP head =================
__global__ __launch_bounds__(256)
void head_k(const float* __restrict__ xc, const in_t* __restrict__ fg, const in_t* __restrict__ fb,
            const in_t* __restrict__ w1, const in_t* __restrict__ b1,
            const in_t* __restrict__ w2, const in_t* __restrict__ b2,
            out_t* __restrict__ outp)
{
  __shared__ float fn[DMODEL];
  __shared__ float hid[64];
  __shared__ float mv[2];
  int b = blockIdx.x, t = threadIdx.x;
  if (t < DMODEL) {
    float m = xc[((size_t)b*6 + 0)*DMODEL + t];
    #pragma unroll
    for (int n = 1; n < 6; ++n) m = fmaxf(m, xc[((size_t)b*6 + n)*DMODEL + t]);
    fn[t] = m;
  }
  __syncthreads();
  if (t == 0) {
    float s = 0.f;
    for (int d = 0; d < DMODEL; ++d) s += fn[d];
    float mean = s / 192.f;
    float v = 0.f;
    for (int d = 0; d < DMODEL; ++d) { float dd = fn[d]-mean; v += dd*dd; }
    mv[0] = mean; mv[1] = 1.f / sqrtf(v/192.f + 1e-6f);
  }
  __syncthreads();
  if (t < DMODEL) fn[t] = (fn[t]-mv[0])*mv[1]*ldi(fg,t) + ldi(fb,t);
  __syncthreads();
  if (t < 64) {
    float a = ldi(b1, t);
    for (int d = 0; d < DMODEL; ++d) a += fn[d]*ldi(w1, (size_t)d*64 + t);
    hid[t] = fmaxf(a, 0.f);
  }
  __syncthreads();
  if (t < 2) {
    float a = ldi(b2, t);
    for (int j = 0; j < 64; ++j) a += hid[j]*ldi(w2, (size_t)j*2 + t);
    outp[(size_t)b*2 + t] = (out_t)a;
  }
}

// =========================================================================
extern "C" void kernel_launch(void* const* d_in, const int* in_sizes, int n_in,
                              void* d_out, int out_size, void* d_ws, size_t ws_size,
                              hipStream_t stream)
{
  if (n_in < 50) return;
  const in_t* x_in     = (const in_t*)d_in[0];
  const in_t* patch_w  = (const in_t*)d_in[1];
  const in_t* patch_b  = (const in_t*)d_in[2];
  const in_t* pos_emb  = (const in_t*)d_in[3];
  const in_t* space_tk = (const in_t*)d_in[4];
  const in_t* temp_tk  = (const in_t*)d_in[5];
  const in_t* s_ln1_g = (const in_t*)d_in[6];  const in_t* s_ln1_b = (const in_t*)d_in[7];
  const in_t* s_qkv_w = (const in_t*)d_in[8];  const in_t* s_out_w = (const in_t*)d_in[9];
  const in_t* s_out_b = (const in_t*)d_in[10]; const in_t* s_ln2_g = (const in_t*)d_in[11];
  const in_t* s_ln2_b = (const in_t*)d_in[12]; const in_t* s_fc1_w = (const in_t*)d_in[13];
  const in_t* s_fc1_b = (const in_t*)d_in[14]; const in_t* s_fc2_w = (const in_t*)d_in[15];
  const in_t* s_fc2_b = (const in_t*)d_in[16]; const in_t* s_nrm_g = (const in_t*)d_in[17];
  const in_t* s_nrm_b = (const in_t*)d_in[18];
  const in_t* t_ln1_g = (const in_t*)d_in[19]; const in_t* t_ln1_b = (const in_t*)d_in[20];
  const in_t* t_qkv_w = (const in_t*)d_in[21]; const in_t* t_out_w = (const in_t*)d_in[22];
  const in_t* t_out_b = (const in_t*)d_in[23]; const in_t* t_ln2_g = (const in_t*)d_in[24];
  const in_t* t_ln2_b = (const in_t*)d_in[25]; const in_t* t_fc1_w = (const in_t*)d_in[26];
  const in_t* t_fc1_b = (const in_t*)d_in[27]; const in_t* t_fc2_w = (const in_t*)d_in[28];
  const in_t* t_fc2_b = (const in_t*)d_in[29]; const in_t* t_nrm_g = (const in_t*)d_in[30];
  const in_t* t_nrm_b = (const in_t*)d_in[31];
  const in_t* a_ln1_g = (const in_t*)d_in[32]; const in_t* a_ln1_b = (const in_t*)d_in[33];
  const in_t* a_qkv_w = (const in_t*)d_in[34]; const in_t* a_qkv_b = (const in_t*)d_in[35];
  const in_t* a_prj_w = (const in_t*)d_in[36]; const in_t* a_prj_b = (const in_t*)d_in[37];
  const in_t* a_ln2_g = (const in_t*)d_in[38]; const in_t* a_ln2_b = (const in_t*)d_in[39];
  const in_t* a_fc1_w = (const in_t*)d_in[40]; const in_t* a_fc1_b = (const in_t*)d_in[41];
  const in_t* a_fc2_w = (const in_t*)d_in[42]; const in_t* a_fc2_b = (const in_t*)d_in[43];
  const in_t* final_g = (const in_t*)d_in[44]; const in_t* final_b = (const in_t*)d_in[45];
  const in_t* h1_w = (const in_t*)d_in[46];    const in_t* h1_b = (const in_t*)d_in[47];
  const in_t* h2_w = (const in_t*)d_in[48];    const in_t* h2_b = (const in_t*)d_in[49];

  float* ws = (float*)d_ws;
  size_t off = 0;
  auto alloc = [&](size_t nf) { size_t r = off; off += (nf + 63) & ~((size_t)63); return r; };
  size_t oX    = alloc((size_t)ROWS_*DMODEL);
  size_t oX2   = alloc((size_t)ROWS_*DMODEL);
  size_t oH    = alloc((size_t)ROWS_*DMODEL);
  size_t oH2   = alloc((size_t)ROWS_*DMODEL);
  size_t oY    = alloc((size_t)ROWS_*384);
  size_t oVf   = alloc((size_t)ROWS_*192);
  size_t oA0   = alloc((size_t)480*NTOK);
  size_t oXC   = alloc((size_t)16*6*DMODEL);
  size_t oIDX  = alloc((size_t)BT_*NTOK);
  size_t oQKVt = alloc((size_t)96*1152);
  size_t oFFt  = alloc((size_t)96*768);
  size_t oWB   = alloc((size_t)4202496 + 64);
  size_t oQKVb = alloc((size_t)ROWS_*1152/2 + 64);
  size_t oYb   = alloc((size_t)ROWS_*384/2 + 64);
  size_t oFFb  = alloc((size_t)ROWS_*768/2 + 64);
  if (ws_size < off*sizeof(float)) return;

  float* X    = ws + oX;
  float* X2   = ws + oX2;
  float* H    = ws + oH;
  float* H2   = ws + oH2;
  float* Y    = ws + oY;
  float* Vf   = ws + oVf;
  float* A0   = ws + oA0;
  float* XC   = ws + oXC;
  int*   IDX  = (int*)(ws + oIDX);
  float* QKVt = ws + oQKVt;
  float* FFt  = ws + oFFt;
  short* WB   = (short*)(ws + oWB);
  short* QKVb = (short*)(ws + oQKVb);
  short* Yb   = (short*)(ws + oYb);
  short* FFb  = (short*)(ws + oFFb);

  size_t wo = 0;
  auto wslot = [&](size_t n){ size_t r = wo; wo += n; return r; };
  size_t wPatch = wslot(147456);
  size_t wSqkv  = wslot(442368);
  size_t wSout  = wslot(147456);
  size_t wSfc1  = wslot(294912);
  size_t wSfc2  = wslot(294912);
  size_t wAqkv  = wslot(1327104);
  size_t wAprj  = wslot(442368);
  size_t wAfc1  = wslot(1769472);
  size_t wAfc2  = wslot(1769472);
  size_t wTqkv  = wslot(663552);
  size_t wTout  = wslot(221184);
  size_t wTfc1  = wslot(442368);
  size_t wTfc2  = wslot(442368);

  auto wconv = [&](const in_t* W, size_t slot, int K, int N, int L) {
    dim3 g(N/32, K/32, L);
    hipLaunchKernelGGL(wconv_k, g, dim3(256), 0, stream, W, WB + slot, K, N);
  };
  wconv(patch_w, wPatch, 768, 192, 1);
  wconv(s_qkv_w, wSqkv, 192, 1152, 2);
  wconv(s_out_w, wSout, 384, 192, 2);
  wconv(s_fc1_w, wSfc1, 192, 768, 2);
  wconv(s_fc2_w, wSfc2, 768, 192, 2);
  wconv(a_qkv_w, wAqkv, 192, 576, 12);
  wconv(a_prj_w, wAprj, 192, 192, 12);
  wconv(a_fc1_w, wAfc1, 192, 768, 12);
  wconv(a_fc2_w, wAfc2, 768, 192, 12);
  wconv(t_qkv_w, wTqkv, 192, 1152, 3);
  wconv(t_out_w, wTout, 384, 192, 3);
  wconv(t_fc1_w, wTfc1, 192, 768, 3);
  wconv(t_fc2_w, wTfc2, 768, 192, 3);

  auto gemm = [&](int epi, int abf, int obf, const void* A, const short* Wt,
                  const float* bias, const float* R, void* C, float* C2,
                  int M, int N, int K) {
    dim3 grid(N/64, (M+63)/64);
    if (obf==2)                        hipLaunchKernelGGL((gemmW_k<0,0,2>), grid, dim3(256), 0, stream, A, Wt, bias, R, C, C2, M, N, K);
    else if (epi==0 && abf==0 && obf==0) hipLaunchKernelGGL((gemmW_k<0,0,0>), grid, dim3(256), 0, stream, A, Wt, bias, R, C, C2, M, N, K);
    else if (epi==0 && abf==0 && obf==1) hipLaunchKernelGGL((gemmW_k<0,0,1>), grid, dim3(256), 0, stream, A, Wt, bias, R, C, C2, M, N, K);
    else if (epi==0 && abf==1 && obf==0) hipLaunchKernelGGL((gemmW_k<0,1,0>), grid, dim3(256), 0, stream, A, Wt, bias, R, C, C2, M, N, K);
    else if (epi==1 && obf==1)         hipLaunchKernelGGL((gemmW_k<1,0,1>), grid, dim3(256), 0, stream, A, Wt, bias, R, C, C2, M, N, K);
    else if (epi==1)                   hipLaunchKernelGGL((gemmW_k<1,0,0>), grid, dim3(256), 0, stream, A, Wt, bias, R, C, C2, M, N, K);
    else if (epi==2 && abf==1)         hipLaunchKernelGGL((gemmW_k<2,1,0>), grid, dim3(256), 0, stream, A, Wt, bias, R, C, C2, M, N, K);
    else                               hipLaunchKernelGGL((gemmW_k<2,0,0>), grid, dim3(256), 0, stream, A, Wt, bias, R, C, C2, M, N, K);
  };
  auto ln = [&](const float* xi, const in_t* g, const in_t* b, float* o, int rows) {
    hipLaunchKernelGGL(ln_k, dim3((rows+3)/4), dim3(256), 0, stream, xi, g, b, o, rows);
  };
  auto ffn = [&](const float* A, size_t w1, const float* b1, size_t w2, const float* b2,
                 const float* R, float* C, int M) {
    hipLaunchKernelGGL(ffn_k, dim3((M+63)/64), dim3(256), 0, stream,
                       A, WB + w1, b1, WB + w2, b2, R, C, M);
  };

  // ---- 1. patch embedding ----
  {
    int total = BT_*196*768;
    hipLaunchKernelGGL(patchify_k, dim3((total+255)/256), dim3(256), 0, stream, x_in, FFb);
    gemm(0, 1, 0, FFb, WB + wPatch, patch_b, nullptr, Y, nullptr, 15680, 192, 768);
    int tot2 = BT_*NTOK*DMODEL;
    hipLaunchKernelGGL(assemble_k, dim3((tot2+255)/256), dim3(256), 0, stream, Y, space_tk, pos_emb, X);
  }

  const float sc64 = 0.125f;
  const float sc32 = 0.17677669529663687f;

  // ---- 2. spatial transformer (2 layers, heads=6, dh=64) ----
  for (int i = 0; i < 2; ++i) {
    ln(X, s_ln1_g + (size_t)i*192, s_ln1_b + (size_t)i*192, H, ROWS_);
    gemm(0, 0, 1, H, WB + wSqkv + (size_t)i*192*1152, nullptr, nullptr, QKVb, nullptr, ROWS_, 1152, 192);
    hipLaunchKernelGGL((attnB_k<64,8,1>), dim3(BT_*6), dim3(512), 0, stream, QKVb, (const float*)nullptr, Yb, (float*)nullptr, 6, sc64);
    gemm(2, 1, 0, Yb, WB + wSout + (size_t)i*384*192, s_out_b + (size_t)i*192, X, X, nullptr, ROWS_, 192, 384);
    ln(X, s_ln2_g + (size_t)i*192, s_ln2_b + (size_t)i*192, H, ROWS_);
    ffn(H, wSfc1 + (size_t)i*192*768, s_fc1_b + (size_t)i*768,
        wSfc2 + (size_t)i*768*192, s_fc2_b + (size_t)i*192, X, X, ROWS_);
  }
  ln(X, s_nrm_g, s_nrm_b, X, ROWS_);

  // ---- 3. ATS blocks (12 layers, heads=6, dh=32) ----
  float* xa = X; float* xb = X2;
  for (int i = 0; i < 12; ++i) {
    ln(xa, a_ln1_g + (size_t)i*192, a_ln1_b + (size_t)i*192, H, ROWS_);
    gemm(0, 0, 2, H, WB + wAqkv + (size_t)i*192*576, a_qkv_b + (size_t)i*576, nullptr, QKVb, Vf, ROWS_, 576, 192);
    hipLaunchKernelGGL((attnB_k<32,4,2>), dim3(BT_*6), dim3(256), 0, stream, QKVb, Vf, Yb, A0, 6, sc32);
    gemm(0, 1, 0, Yb, WB + wAprj + (size_t)i*192*192, a_prj_b + (size_t)i*192, nullptr, H, nullptr, ROWS_, 192, 192);
    hipLaunchKernelGGL(scoresample_k, dim3(BT_), dim3(256), 0, stream, A0, Vf, IDX);
    hipLaunchKernelGGL(gatherln_k, dim3((ROWS_+3)/4), dim3(256), 0, stream,
                       xa, H, IDX, a_ln2_g + (size_t)i*192, a_ln2_b + (size_t)i*192, xb, H2, ROWS_);
    ffn(H2, wAfc1 + (size_t)i*192*768, a_fc1_b + (size_t)i*768,
        wAfc2 + (size_t)i*768*192, a_fc2_b + (size_t)i*192, xb, xb, ROWS_);
    float* tmp = xa; xa = xb; xb = tmp;
  }

  // ---- 4. temporal transformer (3 layers on [16,6,192], fp32 path) ----
  {
    int tot = 16*6*DMODEL;
    hipLaunchKernelGGL(build_xc_k, dim3((tot+255)/256), dim3(256), 0, stream, xa, temp_tk, XC);
  }
  const int MT = 16*6;
  for (int i = 0; i < 3; ++i) {
    ln(XC, t_ln1_g + (size_t)i*192, t_ln1_b + (size_t)i*192, H, MT);
    gemm(0, 0, 0, H, WB + wTqkv + (size_t)i*192*1152, nullptr, nullptr, QKVt, nullptr, MT, 1152, 192);
    hipLaunchKernelGGL((attn2r_k<64,8>), dim3(16*6), dim3(512), 0, stream, QKVt, Y, (float*)nullptr, 6, 6, sc64);
    gemm(2, 0, 0, Y, WB + wTout + (size_t)i*384*192, t_out_b + (size_t)i*192, XC, XC, nullptr, MT, 192, 384);
    ln(XC, t_ln2_g + (size_t)i*192, t_ln2_b + (size_t)i*192, H, MT);
    gemm(1, 0, 0, H, WB + wTfc1 + (size_t)i*192*768, t_fc1_b + (size_t)i*768, nullptr, FFt, nullptr, MT, 768, 192);
    gemm(2, 0, 0, FFt, WB + wTfc2 + (size_t)i*768*192, t_fc2_b + (size_t)i*192, XC, XC, nullptr, MT, 192, 768);
  }
  ln(XC, t_nrm_g, t_nrm_b, XC, MT);

  // ---- 5. maxpool + final LN + head ----
  hipLaunchKernelGGL(head_k, dim3(16), dim3(256), 0, stream, XC, final_g, final_b,
                     h1_w, h1_b, h2_w, h2_b, (out_t*)d_out);
}

// Round 17
// 2465.650 us; speedup vs baseline: 1.3853x; 1.3853x over previous
//
#include <hip/hip_runtime.h>
#include <hip/hip_bf16.h>
#include <math.h>

typedef float in_t;
typedef float out_t;

__device__ __forceinline__ float ldi(const in_t* p, size_t i) { return (float)p[i]; }

#define DMODEL 192
#define NTOK   197
#define BT_    80
#define ROWS_  (BT_*NTOK)   // 15760

__device__ __forceinline__ float gelu_f(float v) {
  return 0.5f*v*(1.f + tanhf(0.7978845608028654f*(v + 0.044715f*v*v*v)));
}

__device__ __forceinline__ short f2bf(float f) {
  union { float f; unsigned u; } v; v.f = f;
  unsigned r = v.u + 0x7FFFu + ((v.u >> 16) & 1u);
  return (short)(r >> 16);
}

typedef __attribute__((ext_vector_type(8))) short bfrag;
typedef __attribute__((ext_vector_type(4))) float f32x4;

// ============ weight convert+transpose: W[l][K][N] fp32 -> O[l][N][K] bf16 ====
__global__ __launch_bounds__(256)
void wconv_k(const float* __restrict__ W, short* __restrict__ O, int K, int N)
{
  __shared__ float tile[32][33];
  const int l = blockIdx.z;
  const int k0 = blockIdx.y*32, n0 = blockIdx.x*32;
  const float* Wl = W + (size_t)l*K*N;
  short* Ol = O + (size_t)l*K*N;
  const int tx = threadIdx.x & 31, ty = threadIdx.x >> 5;
  #pragma unroll
  for (int r = ty; r < 32; r += 8) {
    int k = k0 + r, n = n0 + tx;
    tile[r][tx] = (k < K && n < N) ? Wl[(size_t)k*N + n] : 0.f;
  }
  __syncthreads();
  #pragma unroll
  for (int r = ty; r < 32; r += 8) {
    int n = n0 + r, k = k0 + tx;
    if (n < N && k < K) Ol[(size_t)n*K + k] = f2bf(tile[tx][r]);
  }
}

// ============ gemmW: full-K-chunk (192) staged MFMA GEMM ====================
template<int EPI, int ABF, int OBF>
__global__ __launch_bounds__(256)
void gemmW_k(const void* __restrict__ Ain, const short* __restrict__ Wt,
             const float* __restrict__ bias, const float* __restrict__ R,
             void* __restrict__ Cout, float* __restrict__ Cout2,
             int M, int N, int K)
{
  constexpr int LP = 200;
  __shared__ short Asb[64][LP];
  __shared__ short Bsb[64][LP];
  const int t = threadIdx.x;
  const int w = t >> 6, lane = t & 63;
  const int bm0 = blockIdx.y*64, bn0 = blockIdx.x*64;
  const int sr = t >> 2;
  const int sk = (t & 3) * 8;
  f32x4 acc[4] = {};

  for (int k0 = 0; k0 < K; k0 += 192) {
    const int gm = bm0 + sr;
    #pragma unroll
    for (int cc = 0; cc < 6; ++cc) {
      const int kk = cc*32 + sk;
      short y[8] = {0,0,0,0,0,0,0,0};
      if (gm < M) {
        if (ABF == 0) {
          const float* ap = (const float*)Ain + (size_t)gm*K + k0 + kk;
          float4 v0 = *(const float4*)ap;
          float4 v1 = *(const float4*)(ap + 4);
          y[0]=f2bf(v0.x); y[1]=f2bf(v0.y); y[2]=f2bf(v0.z); y[3]=f2bf(v0.w);
          y[4]=f2bf(v1.x); y[5]=f2bf(v1.y); y[6]=f2bf(v1.z); y[7]=f2bf(v1.w);
        } else {
          *(bfrag*)y = *(const bfrag*)((const short*)Ain + (size_t)gm*K + k0 + kk);
        }
      }
      *(bfrag*)&Asb[sr][kk] = *(bfrag*)y;
      bfrag bv = *(const bfrag*)(Wt + (size_t)(bn0 + sr)*K + k0 + kk);
      *(bfrag*)&Bsb[sr][kk] = bv;
    }
    __syncthreads();
    const int fr = lane & 15, g8 = (lane >> 4) * 8;
    #pragma unroll
    for (int ks = 0; ks < 6; ++ks) {
      bfrag af = *(const bfrag*)&Asb[w*16 + fr][ks*32 + g8];
      #pragma unroll
      for (int nt = 0; nt < 4; ++nt) {
        bfrag bf = *(const bfrag*)&Bsb[nt*16 + fr][ks*32 + g8];
        acc[nt] = __builtin_amdgcn_mfma_f32_16x16x32_bf16(af, bf, acc[nt], 0, 0, 0);
      }
    }
    __syncthreads();
  }
  const int col = lane & 15, rg = (lane >> 4) * 4;
  #pragma unroll
  for (int nt = 0; nt < 4; ++nt) {
    int gn = bn0 + nt*16 + col;
    float bv = bias ? bias[gn] : 0.f;
    #pragma unroll
    for (int r = 0; r < 4; ++r) {
      int gm = bm0 + w*16 + rg + r;
      if (gm < M) {
        float v = acc[nt][r] + bv;
        if (EPI==1) v = gelu_f(v);
        if (EPI==2) v += R[(size_t)gm*N + gn];
        if (OBF==0)      ((float*)Cout)[(size_t)gm*N + gn] = v;
        else if (OBF==1) ((short*)Cout)[(size_t)gm*N + gn] = f2bf(v);
        else {
          if (gn < 384) ((short*)Cout)[(size_t)gm*384 + gn] = f2bf(v);
          else          Cout2[(size_t)gm*192 + (gn - 384)] = v;
        }
      }
    }
  }
}

// ============ ffn_k v3: round-15 staged fused FFN at 8 waves ===============
// Identical numerics to round-15 ffn (same per-output-tile MFMA chains,
// same FF bf16 values); nt-tiles split across wave pairs (band = w&3,
// nh = w>>2) so the 150KB/1-block kernel runs 2 waves/SIMD instead of 1.
__global__ __launch_bounds__(512)
void ffn_k(const float* __restrict__ Ain, const short* __restrict__ W1t,
           const float* __restrict__ b1, const short* __restrict__ W2t,
           const float* __restrict__ b2, const float* __restrict__ R,
           float* __restrict__ Cout, int M)
{
  __shared__ short As[64][200];
  __shared__ short Bs[64][200];
  __shared__ short FF[64][776];
  const int t = threadIdx.x;
  const int w = t >> 6, lane = t & 63;
  const int bm0 = blockIdx.x*64;
  const int sr = t >> 3;            // 0..63 (512 threads)
  const int sk8 = (t & 7) * 8;      // 0..56
  const int fr = lane & 15, g8 = (lane >> 4) * 8;
  const int col = lane & 15, rg = (lane >> 4) * 4;
  const int band = w & 3, nh = w >> 2;
  const int row = band*16 + fr;

  // ---- stage A (64 x 192, fp32 -> bf16) ----
  {
    const int gm = bm0 + sr;
    #pragma unroll
    for (int cc = 0; cc < 3; ++cc) {
      const int kk = cc*64 + sk8;
      short y[8] = {0,0,0,0,0,0,0,0};
      if (gm < M) {
        const float* ap = Ain + (size_t)gm*192 + kk;
        float4 v0 = *(const float4*)ap;
        float4 v1 = *(const float4*)(ap + 4);
        y[0]=f2bf(v0.x); y[1]=f2bf(v0.y); y[2]=f2bf(v0.z); y[3]=f2bf(v0.w);
        y[4]=f2bf(v1.x); y[5]=f2bf(v1.y); y[6]=f2bf(v1.z); y[7]=f2bf(v1.w);
      }
      *(bfrag*)&As[sr][kk] = *(bfrag*)y;
    }
  }
  __syncthreads();

  // ---- fc1: 12 n-chunks of 64; wave computes nt = nh*2 + {0,1} ----
  for (int nc = 0; nc < 12; ++nc) {
    #pragma unroll
    for (int cc = 0; cc < 3; ++cc) {
      const int kk = cc*64 + sk8;
      bfrag bv = *(const bfrag*)(W1t + (size_t)(nc*64 + sr)*192 + kk);
      *(bfrag*)&Bs[sr][kk] = bv;
    }
    __syncthreads();
    f32x4 a1[2] = {};
    #pragma unroll
    for (int ks = 0; ks < 6; ++ks) {
      bfrag af = *(const bfrag*)&As[row][ks*32 + g8];
      #pragma unroll
      for (int ntl = 0; ntl < 2; ++ntl) {
        bfrag bf = *(const bfrag*)&Bs[(nh*2+ntl)*16 + fr][ks*32 + g8];
        a1[ntl] = __builtin_amdgcn_mfma_f32_16x16x32_bf16(af, bf, a1[ntl], 0, 0, 0);
      }
    }
    #pragma unroll
    for (int ntl = 0; ntl < 2; ++ntl) {
      int gn = nc*64 + (nh*2+ntl)*16 + col;
      float bv = b1[gn];
      #pragma unroll
      for (int r = 0; r < 4; ++r)
        FF[band*16 + rg + r][gn] = f2bf(gelu_f(a1[ntl][r] + bv));
    }
    __syncthreads();
  }

  // ---- fc2: tiles (nc,ntl) -> global tile nc*4 + nh*2 + ntl; kc ascending ----
  f32x4 acc2[6] = {};
  for (int kc = 0; kc < 4; ++kc) {
    for (int nc = 0; nc < 3; ++nc) {
      #pragma unroll
      for (int cc = 0; cc < 3; ++cc) {
        const int kk = cc*64 + sk8;
        bfrag bv = *(const bfrag*)(W2t + (size_t)(nc*64 + sr)*768 + kc*192 + kk);
        *(bfrag*)&Bs[sr][kk] = bv;
      }
      __syncthreads();
      #pragma unroll
      for (int ks = 0; ks < 6; ++ks) {
        bfrag af = *(const bfrag*)&FF[row][kc*192 + ks*32 + g8];
        #pragma unroll
        for (int ntl = 0; ntl < 2; ++ntl) {
          bfrag bf = *(const bfrag*)&Bs[(nh*2+ntl)*16 + fr][ks*32 + g8];
          acc2[nc*2+ntl] = __builtin_amdgcn_mfma_f32_16x16x32_bf16(af, bf, acc2[nc*2+ntl], 0, 0, 0);
        }
      }
      __syncthreads();
    }
  }
  // ---- epilogue: bias + residual ----
  #pragma unroll
  for (int nc = 0; nc < 3; ++nc) {
    #pragma unroll
    for (int ntl = 0; ntl < 2; ++ntl) {
      int gn = (nc*4 + nh*2 + ntl)*16 + col;
      float bv = b2[gn];
      #pragma unroll
      for (int r = 0; r < 4; ++r) {
        int gm = bm0 + band*16 + rg + r;
        if (gm < M) {
          float v = acc2[nc*2+ntl][r] + bv + R[(size_t)gm*192 + gn];
          Cout[(size_t)gm*192 + gn] = v;
        }
      }
    }
  }
}

// ================= LayerNorm over width 192 =================
__global__ __launch_bounds__(256)
void ln_k(const float* __restrict__ x, const in_t* __restrict__ g, const in_t* __restrict__ b,
          float* __restrict__ o, int rows)
{
  int t = threadIdx.x, wave = t>>6, lane = t&63;
  int r = blockIdx.x*4 + wave;
  if (r >= rows) return;
  const float* xr = x + (size_t)r*DMODEL;
  float e0 = xr[lane], e1 = xr[lane+64], e2 = xr[lane+128];
  float s = e0+e1+e2;
  #pragma unroll
  for (int off=32; off; off>>=1) s += __shfl_xor(s, off);
  float mean = s / 192.f;
  float d0=e0-mean, d1=e1-mean, d2=e2-mean;
  float v = d0*d0+d1*d1+d2*d2;
  #pragma unroll
  for (int off=32; off; off>>=1) v += __shfl_xor(v, off);
  float rs = 1.f / sqrtf(v/192.f + 1e-6f);
  float* orow = o + (size_t)r*DMODEL;
  orow[lane]     = d0*rs*ldi(g,lane)     + ldi(b,lane);
  orow[lane+64]  = d1*rs*ldi(g,lane+64)  + ldi(b,lane+64);
  orow[lane+128] = d2*rs*ldi(g,lane+128) + ldi(b,lane+128);
}

// ============ fused gather + LayerNorm ====================================
__global__ __launch_bounds__(256)
void gatherln_k(const float* __restrict__ X, const float* __restrict__ P,
                const int* __restrict__ idx, const in_t* __restrict__ g,
                const in_t* __restrict__ b, float* __restrict__ Xo,
                float* __restrict__ H2, int rows)
{
  int t = threadIdx.x, wave = t>>6, lane = t&63;
  int r = blockIdx.x*4 + wave;
  if (r >= rows) return;
  int bt = r / NTOK, n = r - bt*NTOK;
  int src = idx[(size_t)bt*NTOK + n];
  size_t sb = ((size_t)bt*NTOK + src)*DMODEL;
  float e0 = X[sb+lane]     + P[sb+lane];
  float e1 = X[sb+lane+64]  + P[sb+lane+64];
  float e2 = X[sb+lane+128] + P[sb+lane+128];
  float* xr = Xo + (size_t)r*DMODEL;
  xr[lane] = e0; xr[lane+64] = e1; xr[lane+128] = e2;
  float s = e0+e1+e2;
  #pragma unroll
  for (int off=32; off; off>>=1) s += __shfl_xor(s, off);
  float mean = s / 192.f;
  float d0=e0-mean, d1=e1-mean, d2=e2-mean;
  float v = d0*d0+d1*d1+d2*d2;
  #pragma unroll
  for (int off=32; off; off>>=1) v += __shfl_xor(v, off);
  float rs = 1.f / sqrtf(v/192.f + 1e-6f);
  float* orow = H2 + (size_t)r*DMODEL;
  orow[lane]     = d0*rs*ldi(g,lane)     + ldi(b,lane);
  orow[lane+64]  = d1*rs*ldi(g,lane+64)  + ldi(b,lane+64);
  orow[lane+128] = d2*rs*ldi(g,lane+128) + ldi(b,lane+128);
}

// ================= MFMA fused attention, bf16 operands ====================
template<int DH, int W, int MODE>
__global__ __launch_bounds__(W*64)
void attnB_k(const short* __restrict__ qk, const float* __restrict__ vf,
             short* __restrict__ out, float* __restrict__ attn0,
             int heads, float scale)
{
  constexpr int NSEQ = 197;
  constexpr int NP   = 224;
  constexpr int KG   = DH/8;
  constexpr int CT   = DH/16;
  constexpr int NF   = DH/32;
  __shared__ short Kb[KG][NP][8];
  __shared__ short Vt[NP/8][DH][8];
  __shared__ short Ps[W][NP/8][16][8];

  const int bh = blockIdx.x;
  const int b = bh / heads, h = bh - b*heads;
  const int qks = ((MODE==1) ? 3 : 2)*heads*DH;
  const short* __restrict__ baseqk = qk + (size_t)b*NSEQ*qks;
  const int qo = h*DH, ko = heads*DH + h*DH;
  const int vs = heads*DH;
  const float* __restrict__ basev = (MODE==2) ? (vf + (size_t)b*NSEQ*vs) : nullptr;
  const int vo = (MODE==1) ? (2*heads*DH + h*DH) : (h*DH);
  const int t = threadIdx.x, w = t>>6, lane = t&63;

  {
    short z8[8] = {0,0,0,0,0,0,0,0};
    for (int idx = t; idx < NP*KG; idx += W*64) {
      int j = idx / KG, dg = idx - j*KG;
      bfrag kv = *(bfrag*)z8;
      if (j < NSEQ) kv = *(const bfrag*)(baseqk + (size_t)j*qks + ko + dg*8);
      *(bfrag*)&Kb[dg][j][0] = kv;
    }
  }
  for (int idx = t; idx < NP*DH; idx += W*64) {
    int j = idx / DH, d = idx - j*DH;
    short vv = 0;
    if (j < NSEQ) {
      if (MODE==1) vv = baseqk[(size_t)j*qks + vo + d];
      else         vv = f2bf(basev[(size_t)j*vs + vo + d]);
    }
    Vt[j>>3][d][j&7] = vv;
  }
  __syncthreads();

  const int c = lane & 15, g = lane >> 4, rg = g*4;
  const float NEG = -3.0e38f;

  for (int st = w; st < 13; st += W) {
    const int q0 = st*16;
    int qrow = q0 + c; if (qrow > NSEQ-1) qrow = NSEQ-1;
    bfrag aq[NF];
    {
      const short* qp = baseqk + (size_t)qrow*qks + qo + g*8;
      #pragma unroll
      for (int f = 0; f < NF; ++f) aq[f] = *(const bfrag*)(qp + f*32);
    }
    f32x4 sacc[14];
    #pragma unroll
    for (int jt = 0; jt < 14; ++jt) sacc[jt] = (f32x4){0.f,0.f,0.f,0.f};
    #pragma unroll
    for (int jt = 0; jt < 13; ++jt) {
      #pragma unroll
      for (int f = 0; f < NF; ++f) {
        bfrag bk = *(const bfrag*)&Kb[f*4 + g][jt*16 + c][0];
        sacc[jt] = __builtin_amdgcn_mfma_f32_16x16x32_bf16(aq[f], bk, sacc[jt], 0, 0, 0);
      }
    }
    float m0[4] = {NEG,NEG,NEG,NEG};
    #pragma unroll
    for (int jt = 0; jt < 14; ++jt) {
      const bool valid = (jt < 13) && (jt*16 + c < NSEQ);
      #pragma unroll
      for (int r = 0; r < 4; ++r) {
        float sv = valid ? sacc[jt][r]*scale : NEG;
        sacc[jt][r] = sv;
        m0[r] = fmaxf(m0[r], sv);
      }
    }
    #pragma unroll
    for (int off = 1; off < 16; off <<= 1)
      #pragma unroll
      for (int r = 0; r < 4; ++r) m0[r] = fmaxf(m0[r], __shfl_xor(m0[r], off));
    float sum[4] = {0.f,0.f,0.f,0.f};
    #pragma unroll
    for (int jt = 0; jt < 14; ++jt)
      #pragma unroll
      for (int r = 0; r < 4; ++r) {
        float e = expf(sacc[jt][r] - m0[r]);
        sacc[jt][r] = e;
        sum[r] += e;
      }
    #pragma unroll
    for (int off = 1; off < 16; off <<= 1)
      #pragma unroll
      for (int r = 0; r < 4; ++r) sum[r] += __shfl_xor(sum[r], off);
    float inv[4];
    #pragma unroll
    for (int r = 0; r < 4; ++r) inv[r] = 1.f / sum[r];

    if (attn0 != nullptr && st == 0 && g == 0) {
      #pragma unroll
      for (int jt = 0; jt < 13; ++jt) {
        int j = jt*16 + c;
        if (j < NSEQ) attn0[(size_t)bh*NSEQ + j] = sacc[jt][0]*inv[0];
      }
    }
    #pragma unroll
    for (int jt = 0; jt < 14; ++jt)
      #pragma unroll
      for (int r = 0; r < 4; ++r)
        Ps[w][jt*2 + (c>>3)][rg + r][c&7] = f2bf(sacc[jt][r]);
    f32x4 oacc[CT];
    #pragma unroll
    for (int ct = 0; ct < CT; ++ct) oacc[ct] = (f32x4){0.f,0.f,0.f,0.f};
    #pragma unroll
    for (int kc = 0; kc < 7; ++kc) {
      bfrag ap = *(const bfrag*)&Ps[w][kc*4 + g][c][0];
      #pragma unroll
      for (int ct = 0; ct < CT; ++ct) {
        bfrag bv = *(const bfrag*)&Vt[kc*4 + g][ct*16 + c][0];
        oacc[ct] = __builtin_amdgcn_mfma_f32_16x16x32_bf16(ap, bv, oacc[ct], 0, 0, 0);
      }
    }
    #pragma unroll
    for (int ct = 0; ct < CT; ++ct)
      #pragma unroll
      for (int r = 0; r < 4; ++r) {
        int q = q0 + rg + r;
        if (q < NSEQ)
          out[((size_t)b*NSEQ + q)*(size_t)(heads*DH) + h*DH + ct*16 + c] = f2bf(oacc[ct][r]*inv[r]);
      }
  }
}

// ================= Fused attention v2r (temporal Nseq=6, fp32) ============
template<int DH, int W>
__global__ __launch_bounds__(W*64)
void attn2r_k(const float* __restrict__ qkv, float* __restrict__ out,
              float* __restrict__ attn0, int Nseq, int heads, float scale)
{
  constexpr int QT = 8;
  constexpr int KTS = 204;
  constexpr int NPART = (DH == 64) ? 1 : 2;
  constexpr int DQ   = DH/4;
  constexpr int QPG  = 2;
  __shared__ float Kt[DH * KTS];
  __shared__ float Qt[W][DH][12];
  __shared__ float Ps[W][QT][200];

  const int bh = blockIdx.x;
  const int b = bh / heads, h = bh % heads;
  const int stride = 3 * heads * DH;
  const float* __restrict__ base = qkv + (size_t)b * Nseq * stride;
  const int qo = h * DH, ko = heads * DH + h * DH, vo = 2 * heads * DH + h * DH;
  const int t = threadIdx.x, w = t >> 6, lane = t & 63;

  for (int idx = t; idx < Nseq * DH; idx += W * 64) {
    int j = idx / DH, d0 = idx - j * DH;
    Kt[d0 * KTS + j] = base[(size_t)j * stride + ko + d0];
  }
  __syncthreads();

  const int d = lane & (DH - 1);
  const int nchunks = (Nseq + QT - 1) / QT;
  const int jcmax = (Nseq + 3) >> 2;
  const float NEG = -3.0e38f;
  const float4* Kt4 = (const float4*)Kt;

  const int part = (NPART == 2) ? (lane >> 5) : 0;
  const int qg   = (DH == 64) ? (lane >> 4) : ((lane >> 3) & 3);
  const int dq   = lane & (DQ - 1);
  const int dv   = 4 * dq;

  for (int ic = w; ic < nchunks; ic += W) {
    const int i0 = ic * QT;
    if ((DH == 64) || (lane >> 5) == 0) {
      #pragma unroll
      for (int q = 0; q < QT; ++q) {
        int i = i0 + q;
        Qt[w][d][q] = (i < Nseq) ? base[(size_t)i * stride + qo + d] : 0.f;
      }
    }
    float s[QT][4];
    #pragma unroll
    for (int q = 0; q < QT; ++q)
      #pragma unroll
      for (int u = 0; u < 4; ++u) s[q][u] = 0.f;
    #pragma unroll 4
    for (int dd = 0; dd < DH; ++dd) {
      float4 kv = (lane < 51) ? Kt4[dd * (KTS/4) + lane] : make_float4(0.f,0.f,0.f,0.f);
      float4 qA = *(const float4*)&Qt[w][dd][0];
      float4 qB = *(const float4*)&Qt[w][dd][4];
      float qv[8] = {qA.x, qA.y, qA.z, qA.w, qB.x, qB.y, qB.z, qB.w};
      float kr[4] = {kv.x, kv.y, kv.z, kv.w};
      #pragma unroll
      for (int q = 0; q < QT; ++q)
        #pragma unroll
        for (int u = 0; u < 4; ++u)
          s[q][u] = fmaf(qv[q], kr[u], s[q][u]);
    }
    float inv[QT];
    #pragma unroll
    for (int q = 0; q < QT; ++q) {
      float mx = NEG;
      #pragma unroll
      for (int u = 0; u < 4; ++u) {
        int j = 4*lane + u;
        s[q][u] = (j < Nseq) ? s[q][u]*scale : NEG;
        mx = fmaxf(mx, s[q][u]);
      }
      #pragma unroll
      for (int off = 32; off; off >>= 1) mx = fmaxf(mx, __shfl_xor(mx, off));
      float sum = 0.f;
      #pragma unroll
      for (int u = 0; u < 4; ++u) {
        float p = (4*lane + u < Nseq) ? expf(s[q][u] - mx) : 0.f;
        s[q][u] = p; sum += p;
      }
      #pragma unroll
      for (int off = 32; off; off >>= 1) sum += __shfl_xor(sum, off);
      inv[q] = 1.f / sum;
      if (lane < 50)
        *(float4*)&Ps[w][q][4*lane] = make_float4(s[q][0], s[q][1], s[q][2], s[q][3]);
    }
    if (attn0 != nullptr && i0 == 0) {
      #pragma unroll
      for (int u = 0; u < 4; ++u) {
        int j = 4*lane + u;
        if (j < Nseq) attn0[(size_t)bh*Nseq + j] = s[0][u]*inv[0];
      }
    }
    float o[QPG][4];
    #pragma unroll
    for (int qi = 0; qi < QPG; ++qi) { o[qi][0]=0.f; o[qi][1]=0.f; o[qi][2]=0.f; o[qi][3]=0.f; }
    const float* __restrict__ Vg = base + vo;
    for (int jc = part; jc < jcmax; jc += NPART) {
      const int jb = 4*jc;
      float4 V0 = make_float4(0.f,0.f,0.f,0.f), V1=V0, V2=V0, V3=V0;
      if (jb+0 < Nseq) V0 = *(const float4*)&Vg[(size_t)(jb+0)*stride + dv];
      if (jb+1 < Nseq) V1 = *(const float4*)&Vg[(size_t)(jb+1)*stride + dv];
      if (jb+2 < Nseq) V2 = *(const float4*)&Vg[(size_t)(jb+2)*stride + dv];
      if (jb+3 < Nseq) V3 = *(const float4*)&Vg[(size_t)(jb+3)*stride + dv];
      #pragma unroll
      for (int qi = 0; qi < QPG; ++qi) {
        float4 p4 = *(const float4*)&Ps[w][qg*QPG+qi][jb];
        o[qi][0] = fmaf(p4.w,V3.x, fmaf(p4.z,V2.x, fmaf(p4.y,V1.x, fmaf(p4.x,V0.x, o[qi][0]))));
        o[qi][1] = fmaf(p4.w,V3.y, fmaf(p4.z,V2.y, fmaf(p4.y,V1.y, fmaf(p4.x,V0.y, o[qi][1]))));
        o[qi][2] = fmaf(p4.w,V3.z, fmaf(p4.z,V2.z, fmaf(p4.y,V1.z, fmaf(p4.x,V0.z, o[qi][2]))));
        o[qi][3] = fmaf(p4.w,V3.w, fmaf(p4.z,V2.w, fmaf(p4.y,V1.w, fmaf(p4.x,V0.w, o[qi][3]))));
      }
    }
    if (NPART == 2) {
      #pragma unroll
      for (int qi = 0; qi < QPG; ++qi) {
        o[qi][0] += __shfl_xor(o[qi][0], 32);
        o[qi][1] += __shfl_xor(o[qi][1], 32);
        o[qi][2] += __shfl_xor(o[qi][2], 32);
        o[qi][3] += __shfl_xor(o[qi][3], 32);
      }
    }
    if (part == 0) {
      #pragma unroll
      for (int qi = 0; qi < QPG; ++qi) {
        float iv = inv[qi];
        if (qg == 1) iv = inv[QPG + qi];
        if (qg == 2) iv = inv[2*QPG + qi];
        if (qg == 3) iv = inv[3*QPG + qi];
        int i = i0 + qg*QPG + qi;
        if (i < Nseq) {
          float4 r = make_float4(o[qi][0]*iv, o[qi][1]*iv, o[qi][2]*iv, o[qi][3]*iv);
          *(float4*)&out[((size_t)b*Nseq + i)*(size_t)(heads*DH) + h*DH + dv] = r;
        }
      }
    }
  }
}

// ================= patch extraction (bf16 out) =================
__global__ void patchify_k(const in_t* __restrict__ x, short* __restrict__ A)
{
  int idx = blockIdx.x*256 + threadIdx.x;
  const int total = BT_*196*768;
  if (idx >= total) return;
  int kc = idx % 768;
  int m  = idx / 768;
  int p  = m % 196;
  int bt = m / 196;
  int c  = kc >> 8;
  int py = (kc >> 4) & 15;
  int px = kc & 15;
  int ph = p / 14, pw = p % 14;
  size_t src = (((size_t)bt*3 + c)*224 + (ph*16+py))*224 + (pw*16+px);
  A[idx] = f2bf(ldi(x, src));
}

// ================= assemble tokens =================
__global__ void assemble_k(const float* __restrict__ pt, const in_t* __restrict__ st,
                           const in_t* __restrict__ pe, float* __restrict__ X)
{
  int i = blockIdx.x*256 + threadIdx.x;
  const int total = BT_*NTOK*DMODEL;
  if (i >= total) return;
  int d  = i % DMODEL;
  int n  = (i / DMODEL) % NTOK;
  int bt = i / (DMODEL*NTOK);
  int tt = bt % 5;
  float base = (n == 0) ? ldi(st, d)
                        : pt[((size_t)bt*196 + (n-1))*DMODEL + d];
  X[i] = base + ldi(pe, ((size_t)tt*NTOK + n)*DMODEL + d);
}

// ============ fused ATS score + sampling ==================================
__global__ __launch_bounds__(256)
void scoresample_k(const float* __restrict__ attn0, const float* __restrict__ Vf,
                   int* __restrict__ idxout)
{
  __shared__ float S[196];
  __shared__ float cdf[196];
  int b = blockIdx.x, t = threadIdx.x;
  if (t < 196) {
    int j = t + 1;
    float acc = 0.f;
    #pragma unroll
    for (int h = 0; h < 6; ++h) {
      float a0 = attn0[((size_t)b*6 + h)*NTOK + j];
      const float* v = Vf + ((size_t)b*NTOK + j)*192 + h*32;
      float ss = 0.f;
      #pragma unroll
      for (int d = 0; d < 32; ++d) ss += v[d]*v[d];
      acc += a0 * sqrtf(ss);
    }
    S[t] = acc / 6.0f;
  }
  __syncthreads();
  if (t == 0) {
    float tot = 0.f;
    for (int k = 0; k < 196; ++k) tot += S[k];
    float denom = tot + 1e-8f;
    float run = 0.f;
    for (int k = 0; k < 196; ++k) { run += S[k] / denom; cdf[k] = run; }
    idxout[(size_t)b*NTOK] = 0;
  }
  __syncthreads();
  if (t < 196) {
    float u = ((float)t + 0.5f) / 196.0f;
    int cnt = 0;
    for (int k = 0; k < 196; ++k) cnt += (cdf[k] < u) ? 1 : 0;
    int c = cnt > 195 ? 195 : cnt;
    idxout[(size_t)b*NTOK + 1 + t] = c + 1;
  }
}

// ================= build temporal sequence =================
__global__ void build_xc_k(const float* __restrict__ X, const in_t* __restrict__ tt,
                           float* __restrict__ xc)
{
  int i = blockIdx.x*256 + threadIdx.x;
  const int total = 16*6*DMODEL;
  if (i >= total) return;
  int d = i % DMODEL;
  int n = (i / DMODEL) % 6;
  int b = i / (DMODEL*6);
  xc[i] = (n == 0) ? ldi(tt, d)
                   : X[(((size_t)b*5 + (n-1))*NTOK + 0)*DMODEL + d];
}

// ================= maxpool + final LN + MLP head =================
__global__ __launch_bounds__(256)
void head_k(const float* __restrict__ xc, const in_t* __restrict__ fg, const in_t* __restrict__ fb,
            const in_t* __restrict__ w1, const in_t* __restrict__ b1,
            const in_t* __restrict__ w2, const in_t* __restrict__ b2,
            out_t* __restrict__ outp)
{
  __shared__ float fn[DMODEL];
  __shared__ float hid[64];
  __shared__ float mv[2];
  int b = blockIdx.x, t = threadIdx.x;
  if (t < DMODEL) {
    float m = xc[((size_t)b*6 + 0)*DMODEL + t];
    #pragma unroll
    for (int n = 1; n < 6; ++n) m = fmaxf(m, xc[((size_t)b*6 + n)*DMODEL + t]);
    fn[t] = m;
  }
  __syncthreads();
  if (t == 0) {
    float s = 0.f;
    for (int d = 0; d < DMODEL; ++d) s += fn[d];
    float mean = s / 192.f;
    float v = 0.f;
    for (int d = 0; d < DMODEL; ++d) { float dd = fn[d]-mean; v += dd*dd; }
    mv[0] = mean; mv[1] = 1.f / sqrtf(v/192.f + 1e-6f);
  }
  __syncthreads();
  if (t < DMODEL) fn[t] = (fn[t]-mv[0])*mv[1]*ldi(fg,t) + ldi(fb,t);
  __syncthreads();
  if (t < 64) {
    float a = ldi(b1, t);
    for (int d = 0; d < DMODEL; ++d) a += fn[d]*ldi(w1, (size_t)d*64 + t);
    hid[t] = fmaxf(a, 0.f);
  }
  __syncthreads();
  if (t < 2) {
    float a = ldi(b2, t);
    for (int j = 0; j < 64; ++j) a += hid[j]*ldi(w2, (size_t)j*2 + t);
    outp[(size_t)b*2 + t] = (out_t)a;
  }
}

// =========================================================================
extern "C" void kernel_launch(void* const* d_in, const int* in_sizes, int n_in,
                              void* d_out, int out_size, void* d_ws, size_t ws_size,
                              hipStream_t stream)
{
  if (n_in < 50) return;
  const in_t* x_in     = (const in_t*)d_in[0];
  const in_t* patch_w  = (const in_t*)d_in[1];
  const in_t* patch_b  = (const in_t*)d_in[2];
  const in_t* pos_emb  = (const in_t*)d_in[3];
  const in_t* space_tk = (const in_t*)d_in[4];
  const in_t* temp_tk  = (const in_t*)d_in[5];
  const in_t* s_ln1_g = (const in_t*)d_in[6];  const in_t* s_ln1_b = (const in_t*)d_in[7];
  const in_t* s_qkv_w = (const in_t*)d_in[8];  const in_t* s_out_w = (const in_t*)d_in[9];
  const in_t* s_out_b = (const in_t*)d_in[10]; const in_t* s_ln2_g = (const in_t*)d_in[11];
  const in_t* s_ln2_b = (const in_t*)d_in[12]; const in_t* s_fc1_w = (const in_t*)d_in[13];
  const in_t* s_fc1_b = (const in_t*)d_in[14]; const in_t* s_fc2_w = (const in_t*)d_in[15];
  const in_t* s_fc2_b = (const in_t*)d_in[16]; const in_t* s_nrm_g = (const in_t*)d_in[17];
  const in_t* s_nrm_b = (const in_t*)d_in[18];
  const in_t* t_ln1_g = (const in_t*)d_in[19]; const in_t* t_ln1_b = (const in_t*)d_in[20];
  const in_t* t_qkv_w = (const in_t*)d_in[21]; const in_t* t_out_w = (const in_t*)d_in[22];
  const in_t* t_out_b = (const in_t*)d_in[23]; const in_t* t_ln2_g = (const in_t*)d_in[24];
  const in_t* t_ln2_b = (const in_t*)d_in[25]; const in_t* t_fc1_w = (const in_t*)d_in[26];
  const in_t* t_fc1_b = (const in_t*)d_in[27]; const in_t* t_fc2_w = (const in_t*)d_in[28];
  const in_t* t_fc2_b = (const in_t*)d_in[29]; const in_t* t_nrm_g = (const in_t*)d_in[30];
  const in_t* t_nrm_b = (const in_t*)d_in[31];
  const in_t* a_ln1_g = (const in_t*)d_in[32]; const in_t* a_ln1_b = (const in_t*)d_in[33];
  const in_t* a_qkv_w = (const in_t*)d_in[34]; const in_t* a_qkv_b = (const in_t*)d_in[35];
  const in_t* a_prj_w = (const in_t*)d_in[36]; const in_t* a_prj_b = (const in_t*)d_in[37];
  const in_t* a_ln2_g = (const in_t*)d_in[38]; const in_t* a_ln2_b = (const in_t*)d_in[39];
  const in_t* a_fc1_w = (const in_t*)d_in[40]; const in_t* a_fc1_b = (const in_t*)d_in[41];
  const in_t* a_fc2_w = (const in_t*)d_in[42]; const in_t* a_fc2_b = (const in_t*)d_in[43];
  const in_t* final_g = (const in_t*)d_in[44]; const in_t* final_b = (const in_t*)d_in[45];
  const in_t* h1_w = (const in_t*)d_in[46];    const in_t* h1_b = (const in_t*)d_in[47];
  const in_t* h2_w = (const in_t*)d_in[48];    const in_t* h2_b = (const in_t*)d_in[49];

  float* ws = (float*)d_ws;
  size_t off = 0;
  auto alloc = [&](size_t nf) { size_t r = off; off += (nf + 63) & ~((size_t)63); return r; };
  size_t oX    = alloc((size_t)ROWS_*DMODEL);
  size_t oX2   = alloc((size_t)ROWS_*DMODEL);
  size_t oH    = alloc((size_t)ROWS_*DMODEL);
  size_t oH2   = alloc((size_t)ROWS_*DMODEL);
  size_t oY    = alloc((size_t)ROWS_*384);
  size_t oVf   = alloc((size_t)ROWS_*192);
  size_t oA0   = alloc((size_t)480*NTOK);
  size_t oXC   = alloc((size_t)16*6*DMODEL);
  size_t oIDX  = alloc((size_t)BT_*NTOK);
  size_t oQKVt = alloc((size_t)96*1152);
  size_t oFFt  = alloc((size_t)96*768);
  size_t oWB   = alloc((size_t)4202496 + 64);
  size_t oQKVb = alloc((size_t)ROWS_*1152/2 + 64);
  size_t oYb   = alloc((size_t)ROWS_*384/2 + 64);
  size_t oFFb  = alloc((size_t)ROWS_*768/2 + 64);
  if (ws_size < off*sizeof(float)) return;

  float* X    = ws + oX;
  float* X2   = ws + oX2;
  float* H    = ws + oH;
  float* H2   = ws + oH2;
  float* Y    = ws + oY;
  float* Vf   = ws + oVf;
  float* A0   = ws + oA0;
  float* XC   = ws + oXC;
  int*   IDX  = (int*)(ws + oIDX);
  float* QKVt = ws + oQKVt;
  float* FFt  = ws + oFFt;
  short* WB   = (short*)(ws + oWB);
  short* QKVb = (short*)(ws + oQKVb);
  short* Yb   = (short*)(ws + oYb);
  short* FFb  = (short*)(ws + oFFb);

  size_t wo = 0;
  auto wslot = [&](size_t n){ size_t r = wo; wo += n; return r; };
  size_t wPatch = wslot(147456);
  size_t wSqkv  = wslot(442368);
  size_t wSout  = wslot(147456);
  size_t wSfc1  = wslot(294912);
  size_t wSfc2  = wslot(294912);
  size_t wAqkv  = wslot(1327104);
  size_t wAprj  = wslot(442368);
  size_t wAfc1  = wslot(1769472);
  size_t wAfc2  = wslot(1769472);
  size_t wTqkv  = wslot(663552);
  size_t wTout  = wslot(221184);
  size_t wTfc1  = wslot(442368);
  size_t wTfc2  = wslot(442368);

  auto wconv = [&](const in_t* W, size_t slot, int K, int N, int L) {
    dim3 g(N/32, K/32, L);
    hipLaunchKernelGGL(wconv_k, g, dim3(256), 0, stream, W, WB + slot, K, N);
  };
  wconv(patch_w, wPatch, 768, 192, 1);
  wconv(s_qkv_w, wSqkv, 192, 1152, 2);
  wconv(s_out_w, wSout, 384, 192, 2);
  wconv(s_fc1_w, wSfc1, 192, 768, 2);
  wconv(s_fc2_w, wSfc2, 768, 192, 2);
  wconv(a_qkv_w, wAqkv, 192, 576, 12);
  wconv(a_prj_w, wAprj, 192, 192, 12);
  wconv(a_fc1_w, wAfc1, 192, 768, 12);
  wconv(a_fc2_w, wAfc2, 768, 192, 12);
  wconv(t_qkv_w, wTqkv, 192, 1152, 3);
  wconv(t_out_w, wTout, 384, 192, 3);
  wconv(t_fc1_w, wTfc1, 192, 768, 3);
  wconv(t_fc2_w, wTfc2, 768, 192, 3);

  auto gemm = [&](int epi, int abf, int obf, const void* A, const short* Wt,
                  const float* bias, const float* R, void* C, float* C2,
                  int M, int N, int K) {
    dim3 grid(N/64, (M+63)/64);
    if (obf==2)                        hipLaunchKernelGGL((gemmW_k<0,0,2>), grid, dim3(256), 0, stream, A, Wt, bias, R, C, C2, M, N, K);
    else if (epi==0 && abf==0 && obf==0) hipLaunchKernelGGL((gemmW_k<0,0,0>), grid, dim3(256), 0, stream, A, Wt, bias, R, C, C2, M, N, K);
    else if (epi==0 && abf==0 && obf==1) hipLaunchKernelGGL((gemmW_k<0,0,1>), grid, dim3(256), 0, stream, A, Wt, bias, R, C, C2, M, N, K);
    else if (epi==0 && abf==1 && obf==0) hipLaunchKernelGGL((gemmW_k<0,1,0>), grid, dim3(256), 0, stream, A, Wt, bias, R, C, C2, M, N, K);
    else if (epi==1 && obf==1)         hipLaunchKernelGGL((gemmW_k<1,0,1>), grid, dim3(256), 0, stream, A, Wt, bias, R, C, C2, M, N, K);
    else if (epi==1)                   hipLaunchKernelGGL((gemmW_k<1,0,0>), grid, dim3(256), 0, stream, A, Wt, bias, R, C, C2, M, N, K);
    else if (epi==2 && abf==1)         hipLaunchKernelGGL((gemmW_k<2,1,0>), grid, dim3(256), 0, stream, A, Wt, bias, R, C, C2, M, N, K);
    else                               hipLaunchKernelGGL((gemmW_k<2,0,0>), grid, dim3(256), 0, stream, A, Wt, bias, R, C, C2, M, N, K);
  };
  auto ln = [&](const float* xi, const in_t* g, const in_t* b, float* o, int rows) {
    hipLaunchKernelGGL(ln_k, dim3((rows+3)/4), dim3(256), 0, stream, xi, g, b, o, rows);
  };
  auto ffn = [&](const float* A, size_t w1, const float* b1, size_t w2, const float* b2,
                 const float* R, float* C, int M) {
    hipLaunchKernelGGL(ffn_k, dim3((M+63)/64), dim3(512), 0, stream,
                       A, WB + w1, b1, WB + w2, b2, R, C, M);
  };

  // ---- 1. patch embedding ----
  {
    int total = BT_*196*768;
    hipLaunchKernelGGL(patchify_k, dim3((total+255)/256), dim3(256), 0, stream, x_in, FFb);
    gemm(0, 1, 0, FFb, WB + wPatch, patch_b, nullptr, Y, nullptr, 15680, 192, 768);
    int tot2 = BT_*NTOK*DMODEL;
    hipLaunchKernelGGL(assemble_k, dim3((tot2+255)/256), dim3(256), 0, stream, Y, space_tk, pos_emb, X);
  }

  const float sc64 = 0.125f;
  const float sc32 = 0.17677669529663687f;

  // ---- 2. spatial transformer (2 layers, heads=6, dh=64) ----
  for (int i = 0; i < 2; ++i) {
    ln(X, s_ln1_g + (size_t)i*192, s_ln1_b + (size_t)i*192, H, ROWS_);
    gemm(0, 0, 1, H, WB + wSqkv + (size_t)i*192*1152, nullptr, nullptr, QKVb, nullptr, ROWS_, 1152, 192);
    hipLaunchKernelGGL((attnB_k<64,8,1>), dim3(BT_*6), dim3(512), 0, stream, QKVb, (const float*)nullptr, Yb, (float*)nullptr, 6, sc64);
    gemm(2, 1, 0, Yb, WB + wSout + (size_t)i*384*192, s_out_b + (size_t)i*192, X, X, nullptr, ROWS_, 192, 384);
    ln(X, s_ln2_g + (size_t)i*192, s_ln2_b + (size_t)i*192, H, ROWS_);
    ffn(H, wSfc1 + (size_t)i*192*768, s_fc1_b + (size_t)i*768,
        wSfc2 + (size_t)i*768*192, s_fc2_b + (size_t)i*192, X, X, ROWS_);
  }
  ln(X, s_nrm_g, s_nrm_b, X, ROWS_);

  // ---- 3. ATS blocks (12 layers, heads=6, dh=32) ----
  float* xa = X; float* xb = X2;
  for (int i = 0; i < 12; ++i) {
    ln(xa, a_ln1_g + (size_t)i*192, a_ln1_b + (size_t)i*192, H, ROWS_);
    gemm(0, 0, 2, H, WB + wAqkv + (size_t)i*192*576, a_qkv_b + (size_t)i*576, nullptr, QKVb, Vf, ROWS_, 576, 192);
    hipLaunchKernelGGL((attnB_k<32,4,2>), dim3(BT_*6), dim3(256), 0, stream, QKVb, Vf, Yb, A0, 6, sc32);
    gemm(0, 1, 0, Yb, WB + wAprj + (size_t)i*192*192, a_prj_b + (size_t)i*192, nullptr, H, nullptr, ROWS_, 192, 192);
    hipLaunchKernelGGL(scoresample_k, dim3(BT_), dim3(256), 0, stream, A0, Vf, IDX);
    hipLaunchKernelGGL(gatherln_k, dim3((ROWS_+3)/4), dim3(256), 0, stream,
                       xa, H, IDX, a_ln2_g + (size_t)i*192, a_ln2_b + (size_t)i*192, xb, H2, ROWS_);
    ffn(H2, wAfc1 + (size_t)i*192*768, a_fc1_b + (size_t)i*768,
        wAfc2 + (size_t)i*768*192, a_fc2_b + (size_t)i*192, xb, xb, ROWS_);
    float* tmp = xa; xa = xb; xb = tmp;
  }

  // ---- 4. temporal transformer (3 layers on [16,6,192], fp32 path) ----
  {
    int tot = 16*6*DMODEL;
    hipLaunchKernelGGL(build_xc_k, dim3((tot+255)/256), dim3(256), 0, stream, xa, temp_tk, XC);
  }
  const int MT = 16*6;
  for (int i = 0; i < 3; ++i) {
    ln(XC, t_ln1_g + (size_t)i*192, t_ln1_b + (size_t)i*192, H, MT);
    gemm(0, 0, 0, H, WB + wTqkv + (size_t)i*192*1152, nullptr, nullptr, QKVt, nullptr, MT, 1152, 192);
    hipLaunchKernelGGL((attn2r_k<64,8>), dim3(16*6), dim3(512), 0, stream, QKVt, Y, (float*)nullptr, 6, 6, sc64);
    gemm(2, 0, 0, Y, WB + wTout + (size_t)i*384*192, t_out_b + (size_t)i*192, XC, XC, nullptr, MT, 192, 384);
    ln(XC, t_ln2_g + (size_t)i*192, t_ln2_b + (size_t)i*192, H, MT);
    gemm(1, 0, 0, H, WB + wTfc1 + (size_t)i*192*768, t_fc1_b + (size_t)i*768, nullptr, FFt, nullptr, MT, 768, 192);
    gemm(2, 0, 0, FFt, WB + wTfc2 + (size_t)i*768*192, t_fc2_b + (size_t)i*192, XC, XC, nullptr, MT, 192, 768);
  }
  ln(XC, t_nrm_g, t_nrm_b, XC, MT);

  // ---- 5. maxpool + final LN + head ----
  hipLaunchKernelGGL(head_k, dim3(16), dim3(256), 0, stream, XC, final_g, final_b,
                     h1_w, h1_b, h2_w, h2_b, (out_t*)d_out);
}